// Round 11
// baseline (252.879 us; speedup 1.0000x reference)
//
#include <hip/hip_runtime.h>
#include <hip/hip_bf16.h>

#define N_    2048
#define FIN   256
#define FOUT  128
#define ALPHA 0.01f

typedef short bf16x8 __attribute__((ext_vector_type(8)));
typedef float f32x4  __attribute__((ext_vector_type(4)));

static __device__ __forceinline__ unsigned short f2bf(float x) {
    __hip_bfloat16 h = __float2bfloat16(x);
    return *reinterpret_cast<unsigned short*>(&h);
}
static __device__ __forceinline__ float bf2f(unsigned short u) {
    return __uint_as_float(((unsigned)u) << 16);
}

// ---------------------------------------------------------------------------
// W split -> fragment-major bf16 hi/lo (unchanged, verified R6)
__global__ __launch_bounds__(256) void k_wsplit(
    const float* __restrict__ W, unsigned short* __restrict__ WFhi,
    unsigned short* __restrict__ WFlo)
{
    int idx = blockIdx.x * 256 + threadIdx.x;
    int k = idx >> 7, n = idx & 127;
    float w = W[k * 128 + n];
    unsigned short hi = f2bf(w);
    unsigned short lo = f2bf(w - bf2f(hi));
    int nb = n >> 4, ln = n & 15, ks = k >> 5, lg = (k >> 3) & 3, e = k & 7;
    int off = (((nb * 8 + ks) * 4 + lg) * 16 + ln) * 8 + e;
    WFhi[off] = hi;
    WFlo[off] = lo;
}

// ---------------------------------------------------------------------------
// h = inp @ W via 3-term split-bf16 MFMA (verified R6) + FUSED adj->bitmask
// pack for this block's own 64 rows (replaces the standalone k_pack kernel).
// mask byte (row, w, lg, S) = bits of adj[row][w*512 + S*32 + lg*8 .. +7],
// stored at mask[row*256 + w*64 + lg*16 + S].
__global__ __launch_bounds__(256) void k_lin(
    const float* __restrict__ inp, const int* __restrict__ adj,
    const unsigned short* __restrict__ WFhi, const unsigned short* __restrict__ WFlo,
    const float* __restrict__ av, unsigned short* __restrict__ hF,
    float* __restrict__ s1, float* __restrict__ s2,
    unsigned char* __restrict__ mask)
{
    __shared__ unsigned short Ahi[64 * 256];
    __shared__ unsigned short Alo[64 * 256];

    int g = blockIdx.x;            // 256 blocks
    int b = g & 7;
    int i0 = (g >> 3) << 6;
    int t = threadIdx.x;

    {
        int row = t >> 2;
        const float* src = inp + ((size_t)(b * N_ + i0 + row)) * FIN + (t & 3) * 64;
#pragma unroll
        for (int gseg = 0; gseg < 8; ++gseg) {
            float4 f0 = *reinterpret_cast<const float4*>(src + gseg * 8);
            float4 f1 = *reinterpret_cast<const float4*>(src + gseg * 8 + 4);
            float f[8] = {f0.x, f0.y, f0.z, f0.w, f1.x, f1.y, f1.z, f1.w};
            bf16x8 hi8, lo8;
#pragma unroll
            for (int e = 0; e < 8; ++e) {
                unsigned short h = f2bf(f[e]);
                hi8[e] = (short)h;
                lo8[e] = (short)f2bf(f[e] - bf2f(h));
            }
            int k = (t & 3) * 64 + gseg * 8;
            int off = (row * 512 + k * 2) ^ ((row & 7) << 4);
            *reinterpret_cast<bf16x8*>(reinterpret_cast<char*>(Ahi) + off) = hi8;
            *reinterpret_cast<bf16x8*>(reinterpret_cast<char*>(Alo) + off) = lo8;
        }
    }
    __syncthreads();

    int w = t >> 6, l = t & 63;
    int ln = l & 15, lg = l >> 4;
    const bf16x8* Wh8 = reinterpret_cast<const bf16x8*>(WFhi);
    const bf16x8* Wl8 = reinterpret_cast<const bf16x8*>(WFlo);

    f32x4 acc[8];
#pragma unroll
    for (int nb = 0; nb < 8; ++nb) acc[nb] = (f32x4){0.f, 0.f, 0.f, 0.f};

#pragma unroll
    for (int ks = 0; ks < 8; ++ks) {
        int arow = w * 16 + ln;
        int aoff = (arow * 512 + ks * 64 + lg * 16) ^ ((arow & 7) << 4);
        bf16x8 ahi = *reinterpret_cast<const bf16x8*>(reinterpret_cast<const char*>(Ahi) + aoff);
        bf16x8 alo = *reinterpret_cast<const bf16x8*>(reinterpret_cast<const char*>(Alo) + aoff);
#pragma unroll
        for (int nb = 0; nb < 8; ++nb) {
            int fi = ((nb * 8 + ks) * 4 + lg) * 16 + ln;
            bf16x8 whi = Wh8[fi];
            bf16x8 wlo = Wl8[fi];
            acc[nb] = __builtin_amdgcn_mfma_f32_16x16x32_bf16(ahi, whi, acc[nb], 0, 0, 0);
            acc[nb] = __builtin_amdgcn_mfma_f32_16x16x32_bf16(alo, whi, acc[nb], 0, 0, 0);
            acc[nb] = __builtin_amdgcn_mfma_f32_16x16x32_bf16(ahi, wlo, acc[nb], 0, 0, 0);
        }
    }

    float p1[4] = {0.f, 0.f, 0.f, 0.f}, p2[4] = {0.f, 0.f, 0.f, 0.f};
#pragma unroll
    for (int nb = 0; nb < 8; ++nb) {
        float a1 = av[nb * 16 + ln];
        float a2 = av[FOUT + nb * 16 + ln];
#pragma unroll
        for (int j = 0; j < 4; ++j) {
            p1[j] = fmaf(acc[nb][j], a1, p1[j]);
            p2[j] = fmaf(acc[nb][j], a2, p2[j]);
        }
    }
#pragma unroll
    for (int off = 1; off < 16; off <<= 1)
#pragma unroll
        for (int j = 0; j < 4; ++j) {
            p1[j] += __shfl_xor(p1[j], off);
            p2[j] += __shfl_xor(p2[j], off);
        }
    if (ln == 0) {
#pragma unroll
        for (int j = 0; j < 4; ++j) {
            int row = i0 + w * 16 + lg * 4 + j;
            s1[b * N_ + row] = p1[j];
            s2[b * N_ + row] = p2[j];
        }
    }

    // transpose through LDS (reuse Ahi): T[128 f][68]
    __syncthreads();
    unsigned short* T = Ahi;
#pragma unroll
    for (int nb = 0; nb < 8; ++nb)
#pragma unroll
        for (int j = 0; j < 4; ++j)
            T[(nb * 16 + ln) * 68 + w * 16 + lg * 4 + j] = f2bf(acc[nb][j]);
    __syncthreads();
    {
        int f = t & 127, half = t >> 7;
        int J = (i0 >> 5) + half;
        unsigned short tmp[32];
#pragma unroll
        for (int c = 0; c < 32; ++c) tmp[c] = T[f * 68 + half * 32 + c];
        int4* dst = reinterpret_cast<int4*>(&hF[(((size_t)(b * 64 + J)) * 128 + f) * 32]);
#pragma unroll
        for (int c = 0; c < 4; ++c) dst[c] = reinterpret_cast<const int4*>(tmp)[c];
    }

    // ---- fused adj pack: this block's 64 rows (k_pack's 16B/lane pattern) ----
    // wave w packs row grp*4+w each group; mbuf staged in (now free) Alo.
    unsigned char* mbuf = reinterpret_cast<unsigned char*>(Alo);   // 4 rows x 256 B
    const size_t adj_base = ((size_t)(b * N_ + i0)) * N_;
    for (int grp = 0; grp < 16; ++grp) {
        int row = grp * 4 + w;
        const int4* ap = reinterpret_cast<const int4*>(adj + adj_base + (size_t)row * N_);
#pragma unroll
        for (int p = 0; p < 4; ++p) {    // p = j-chunk (w in attn); cols p*512 + l*8
            int4 x = ap[p * 128 + l * 2];
            int4 y = ap[p * 128 + l * 2 + 1];
            unsigned byte =
                (unsigned)(x.x > 0) | ((unsigned)(x.y > 0) << 1) |
                ((unsigned)(x.z > 0) << 2) | ((unsigned)(x.w > 0) << 3) |
                ((unsigned)(y.x > 0) << 4) | ((unsigned)(y.y > 0) << 5) |
                ((unsigned)(y.z > 0) << 6) | ((unsigned)(y.w > 0) << 7);
            // S = l>>2, lg = l&3  ->  off = p*64 + lg*16 + S
            mbuf[w * 256 + p * 64 + (l & 3) * 16 + (l >> 2)] = (unsigned char)byte;
        }
        __syncthreads();
        if (t < 64) {
            int rr = t >> 4, q = t & 15;
            reinterpret_cast<uint4*>(mask)[
                (((size_t)(b * N_ + i0 + grp * 4 + rr)) * 256 >> 4) + q] =
                reinterpret_cast<const uint4*>(mbuf)[rr * 16 + q];
        }
        __syncthreads();
    }
}

// ---------------------------------------------------------------------------
// k_attn v6 = R6's v2 (best measured attn: mask-based, 32 rows/block, frag
// double-buffer, accb merge) + no-shift softmax (exp cancels in ratio; s2max
// and m_row removed — verified bit-identical absmax in R10).
__global__ __launch_bounds__(256) void k_attn(
    const unsigned int* __restrict__ mask, const unsigned short* __restrict__ hF,
    const float* __restrict__ s1g, const float* __restrict__ s2g,
    float* __restrict__ out)
{
    __shared__ float s2_lds[N_];         // 8 KB
    __shared__ float accb[4][32][128];   // 64 KB (epilogue only)
    __shared__ float l_s[4][32];

    int g = blockIdx.x;                  // 512
    int b = g & 7;                       // XCD-affine
    int i0 = (g >> 3) << 5;              // 32 rows
    int t = threadIdx.x;
    int w = t >> 6, l = t & 63;
    int r = l & 15, lg = l >> 4;
    int jc = w * 512;

    {
        const float4* s2g4 = reinterpret_cast<const float4*>(s2g + b * N_);
        reinterpret_cast<float4*>(s2_lds)[t] = s2g4[t];
        reinterpret_cast<float4*>(s2_lds)[t + 256] = s2g4[t + 256];
    }

    const float s1r0 = s1g[b * N_ + i0 + r];
    const float s1r1 = s1g[b * N_ + i0 + 16 + r];

    uint4 m40 = *reinterpret_cast<const uint4*>(
        reinterpret_cast<const char*>(mask) +
        ((size_t)(b * N_ + i0 + r)) * 256 + w * 64 + lg * 16);
    uint4 m41 = *reinterpret_cast<const uint4*>(
        reinterpret_cast<const char*>(mask) +
        ((size_t)(b * N_ + i0 + 16 + r)) * 256 + w * 64 + lg * 16);
    unsigned mw0[4] = {m40.x, m40.y, m40.z, m40.w};
    unsigned mw1[4] = {m41.x, m41.y, m41.z, m41.w};

    // hv frag (S,q): hF[((b*64 + w*16 + S)*128 + q*16 + r)*32 + lg*8 ..]
    const bf16x8* hv = reinterpret_cast<const bf16x8*>(hF)
        + (((size_t)(b * 64 + w * 16) * 128 + r) * 4 + lg);

    __syncthreads();   // s2_lds ready

    float l0 = 0.f, l1 = 0.f;
    f32x4 acc0[8], acc1[8];
#pragma unroll
    for (int q = 0; q < 8; ++q) {
        acc0[q] = (f32x4){0.f, 0.f, 0.f, 0.f};
        acc1[q] = (f32x4){0.f, 0.f, 0.f, 0.f};
    }

    bf16x8 hA[8], hB[8];
#pragma unroll
    for (int q = 0; q < 8; ++q) hA[q] = hv[q * 64];

#pragma unroll
    for (int S = 0; S < 16; ++S) {
        auto& cur = (S & 1) ? hB : hA;
        auto& nxt = (S & 1) ? hA : hB;
        if (S < 15) {
#pragma unroll
            for (int q = 0; q < 8; ++q) nxt[q] = hv[(S + 1) * 512 + q * 64];
        }
        unsigned byte0 = (mw0[S >> 2] >> ((S & 3) * 8)) & 0xffu;
        unsigned byte1 = (mw1[S >> 2] >> ((S & 3) * 8)) & 0xffu;
        const float* s2b = &s2_lds[jc + S * 32 + lg * 8];
        float4 ca = *reinterpret_cast<const float4*>(s2b);
        float4 cb = *reinterpret_cast<const float4*>(s2b + 4);
        float sv[8] = {ca.x, ca.y, ca.z, ca.w, cb.x, cb.y, cb.z, cb.w};

        bf16x8 af0, af1;
        float ps0 = 0.f, ps1 = 0.f;
#pragma unroll
        for (int e = 0; e < 8; ++e) {
            float v0 = s1r0 + sv[e];
            v0 = fmaxf(v0, ALPHA * v0);
            float p0 = (byte0 & (1u << e)) ? __expf(v0) : 0.f;   // no shift
            ps0 += p0;
            af0[e] = (short)f2bf(p0);
            float v1 = s1r1 + sv[e];
            v1 = fmaxf(v1, ALPHA * v1);
            float p1 = (byte1 & (1u << e)) ? __expf(v1) : 0.f;
            ps1 += p1;
            af1[e] = (short)f2bf(p1);
        }
        l0 += ps0;
        l1 += ps1;
#pragma unroll
        for (int q = 0; q < 8; ++q) {
            acc0[q] = __builtin_amdgcn_mfma_f32_16x16x32_bf16(af0, cur[q], acc0[q], 0, 0, 0);
            acc1[q] = __builtin_amdgcn_mfma_f32_16x16x32_bf16(af1, cur[q], acc1[q], 0, 0, 0);
        }
    }

    l0 += __shfl_xor(l0, 16);
    l0 += __shfl_xor(l0, 32);
    l1 += __shfl_xor(l1, 16);
    l1 += __shfl_xor(l1, 32);
    if (l < 16) {
        l_s[w][l] = l0;
        l_s[w][16 + l] = l1;
    }

#pragma unroll
    for (int q = 0; q < 8; ++q)
#pragma unroll
        for (int rr = 0; rr < 4; ++rr) {
            accb[w][lg * 4 + rr][q * 16 + r] = acc0[q][rr];
            accb[w][16 + lg * 4 + rr][q * 16 + r] = acc1[q][rr];
        }
    __syncthreads();

    int f = t & 127, rh = t >> 7;
#pragma unroll
    for (int rr = 0; rr < 16; ++rr) {
        int row = rh * 16 + rr;
        float L = l_s[0][row] + l_s[1][row] + l_s[2][row] + l_s[3][row];
        float v = accb[0][row][f] + accb[1][row][f] + accb[2][row][f] + accb[3][row][f];
        out[((size_t)(b * N_ + i0 + row)) * FOUT + f] = fmaxf(v / L, 0.f);
    }
}

extern "C" void kernel_launch(void* const* d_in, const int* in_sizes, int n_in,
                              void* d_out, int out_size, void* d_ws, size_t ws_size,
                              hipStream_t stream) {
    (void)in_sizes; (void)n_in; (void)out_size; (void)ws_size;
    const float* inp = (const float*)d_in[0];
    const int*   adj = (const int*)d_in[1];
    const float* W   = (const float*)d_in[2];
    const float* a   = (const float*)d_in[3];
    float* out = (float*)d_out;

    char* ws = (char*)d_ws;
    unsigned short* hF   = (unsigned short*)ws;                         // 4 MB
    unsigned char*  mask = (unsigned char*)(ws + (4u << 20));           // 4 MB
    float* s1    = (float*)(ws + (8u << 20));                           // 64 KB
    float* s2    = s1 + 8 * N_;                                         // 64 KB
    unsigned short* WFhi = (unsigned short*)(s2 + 8 * N_);              // 64 KB
    unsigned short* WFlo = WFhi + FIN * FOUT;                           // 64 KB

    k_wsplit<<<128, 256, 0, stream>>>(W, WFhi, WFlo);
    k_lin<<<256, 256, 0, stream>>>(inp, adj, WFhi, WFlo, a, hF, s1, s2, mask);
    k_attn<<<512, 256, 0, stream>>>((const unsigned int*)mask, hF, s1, s2, out);
}